// Round 17
// baseline (2927.706 us; speedup 1.0000x reference)
//
#include <hip/hip_runtime.h>
#include <stdio.h>

#define NN 20000
#define NE 640000
#define NL 10

typedef unsigned short u16;
typedef unsigned int u32;
typedef __attribute__((ext_vector_type(8))) __bf16 bf16x8;
typedef __attribute__((ext_vector_type(2))) __bf16 bf16x2;
typedef __attribute__((ext_vector_type(8))) unsigned short us8;
typedef __attribute__((ext_vector_type(4))) float f32x4;

__device__ __forceinline__ bf16x8 ldbf(const u16* p) {
  union { us8 u; bf16x8 b; } v;
  v.u = *(const us8*)p;
  return v.b;
}
__device__ __forceinline__ f32x4 zero4() {
  f32x4 z; z[0] = 0.f; z[1] = 0.f; z[2] = 0.f; z[3] = 0.f; return z;
}
__device__ __forceinline__ float bf2f(u16 u) {
  u32 x = ((u32)u) << 16;
  return __uint_as_float(x);
}
// native cast -> v_cvt_pk_bf16_f32 (RTNE, bit-identical to manual RNE)
__device__ __forceinline__ u16 f2bf(float f) {
  __bf16 b = (__bf16)f;
  union { __bf16 b; u16 u; } v;
  v.b = b;
  return v.u;
}
__device__ __forceinline__ u32 cvt2(float lo, float hi) {
  union { bf16x2 b; u32 u; } v;
  v.b[0] = (__bf16)lo; v.b[1] = (__bf16)hi;
  return v.u;
}
// swizzled LDS element index for a [R][128] bf16 tile; 16B-chunk XOR swizzle
// (valid for any row count; swizzle period is 16 rows)
__device__ __forceinline__ int lad(int row, int col) {
  return (row << 7) + ((((col >> 3) ^ (row & 15)) << 3) | (col & 7));
}
__device__ __forceinline__ uint2 pack4bf(const float f[4]) {
  uint2 u;
  u.x = cvt2(f[0], f[1]);
  u.y = cvt2(f[2], f[3]);
  return u;
}
__device__ __forceinline__ void unpack4bf(uint2 u, float f[4]) {
  f[0] = bf2f((u16)(u.x & 0xffffu)); f[1] = bf2f((u16)(u.x >> 16));
  f[2] = bf2f((u16)(u.y & 0xffffu)); f[3] = bf2f((u16)(u.y >> 16));
}

// stub-named kernel retained (inert).
__global__ void LearnedSimModel_28716151341396_kernel() {}

// zero agg + dst histogram counters
__global__ void init_kernel(float* agg, int agg_n, int* cnt, int cnt_n) {
  int i = blockIdx.x * 256 + threadIdx.x;
  if (i < agg_n) agg[i] = 0.0f;
  if (i < cnt_n) cnt[i] = 0;
}

__global__ void idx_detect_kernel(const int* raw, int* flag) {
  if (threadIdx.x == 0 && blockIdx.x == 0) {
    int any = 0;
    for (int k = 0; k < 16; ++k) any = any | raw[2 * k + 1];
    flag[0] = (any != 0) ? 1 : 0;  // 1 -> int32 storage
  }
}

__global__ void idx_prep_kernel(const int* raw, const int* flag, int* idx0) {
  int i = blockIdx.x * 256 + threadIdx.x;
  if (i < 2 * NE) {
    int v;
    if (flag[0] != 0) v = raw[i];
    else v = (int)(((const long long*)raw)[i]);
    if (v < 0) v = 0;
    if (v >= NN) v = NN - 1;
    idx0[i] = v;
  }
}

__global__ void hist_kernel(const int* dst0, int* cnt) {
  int i = blockIdx.x * 256 + threadIdx.x;
  if (i < NE) atomicAdd(&cnt[dst0[i]], 1);
}

// exclusive prefix sum of cnt[NN] -> cursor[NN] (single block, 1024 threads)
__global__ void prefix_kernel(const int* cnt, int* cursor) {
  __shared__ int buf[1024];
  __shared__ int carry;
  int t = threadIdx.x;
  if (t == 0) carry = 0;
  __syncthreads();
  for (int base = 0; base < NN; base += 1024) {
    int v = (base + t < NN) ? cnt[base + t] : 0;
    buf[t] = v;
    __syncthreads();
    for (int s = 1; s < 1024; s <<= 1) {
      int add = (t >= s) ? buf[t - s] : 0;
      __syncthreads();
      buf[t] += add;
      __syncthreads();
    }
    int excl = buf[t] - v + carry;
    if (base + t < NN) cursor[base + t] = excl;
    __syncthreads();
    if (t == 0) carry = carry + buf[1023];
    __syncthreads();
  }
}

// scatter edges into dst-sorted order; perm[pos] = original edge id
__global__ void scatter_kernel(const int* src0, const int* dst0, int* cursor,
                               int* src_s, int* dst_s, int* perm) {
  int i = blockIdx.x * 256 + threadIdx.x;
  if (i < NE) {
    int d = dst0[i];
    int pos = atomicAdd(&cursor[d], 1);
    perm[pos] = i;
    src_s[pos] = src0[i];
    dst_s[pos] = d;
  }
}

// 128x128 K-slice transpose: Wt[f*128+k] = f2bf(W[(koff+k)*128 + f])
__global__ void transpose_slice_kernel(const float* __restrict__ W,
                                       u16* __restrict__ Wt, int koff) {
  int i = blockIdx.x * 256 + threadIdx.x;  // i < 128*128
  int k = i >> 7, f = i & 127;
  Wt[f * 128 + k] = f2bf(W[(size_t)(koff + k) * 128 + f]);
}

// node encoder: h f32 only
__global__ void node_enc_kernel(const float* x, const float* noise,
                                const float* w1, const float* b1,
                                const float* w2, const float* b2,
                                float* h) {
  __shared__ float in16[16];
  __shared__ float t1s[128];
  int f = threadIdx.x;
  int n = blockIdx.x;
  if (f < 16) in16[f] = x[n * 16 + f] + noise[n * 16 + f];
  __syncthreads();
  float a = b1[f];
  for (int k = 0; k < 16; ++k) a += in16[k] * w1[k * 128 + f];
  t1s[f] = fmaxf(a, 0.0f);
  __syncthreads();
  float o = b2[f];
  for (int k = 0; k < 128; ++k) o += t1s[k] * w2[k * 128 + f];
  h[(long long)n * 128 + f] = o;
}

// per-wave GEMM over a [64][128] swizzled LDS tile; A = Wt (stride K=128)
__device__ __forceinline__ void gemm128(const u16* lds, const u16* Wt,
                                        int l16, int quad, int fb, f32x4 acc[2][4]) {
  for (int ks = 0; ks < 4; ++ks) {
    int kg = ks * 32 + quad * 8;
    bf16x8 b0 = ldbf(lds + lad(0 * 16 + l16, kg));
    bf16x8 b1 = ldbf(lds + lad(1 * 16 + l16, kg));
    bf16x8 b2 = ldbf(lds + lad(2 * 16 + l16, kg));
    bf16x8 b3 = ldbf(lds + lad(3 * 16 + l16, kg));
    for (int tt = 0; tt < 2; ++tt) {
      bf16x8 a = ldbf(Wt + (size_t)(fb + tt * 16 + l16) * 128 + kg);
      acc[tt][0] = __builtin_amdgcn_mfma_f32_16x16x32_bf16(a, b0, acc[tt][0], 0, 0, 0);
      acc[tt][1] = __builtin_amdgcn_mfma_f32_16x16x32_bf16(a, b1, acc[tt][1], 0, 0, 0);
      acc[tt][2] = __builtin_amdgcn_mfma_f32_16x16x32_bf16(a, b2, acc[tt][2], 0, 0, 0);
      acc[tt][3] = __builtin_amdgcn_mfma_f32_16x16x32_bf16(a, b3, acc[tt][3], 0, 0, 0);
    }
  }
}

// 8-wave/128-edge GEMM: wave owns 16 output features, 8 row-groups of 16 edges
__device__ __forceinline__ void gemm128x8(const u16* lds, const u16* Wt,
                                          int l16, int quad, int fb, f32x4 acc[8]) {
  for (int ks = 0; ks < 4; ++ks) {
    int kg = ks * 32 + quad * 8;
    bf16x8 a = ldbf(Wt + (size_t)(fb + l16) * 128 + kg);
#pragma unroll
    for (int et = 0; et < 8; ++et) {
      bf16x8 b = ldbf(lds + lad(et * 16 + l16, kg));
      acc[et] = __builtin_amdgcn_mfma_f32_16x16x32_bf16(a, b, acc[et], 0, 0, 0);
    }
  }
}

// ---------------- MFMA edge encoder: 64 sorted edges/block, 256 threads -----
// writes e in swizzled tile format: e_tile[b][lad(row,f)]
__global__ __launch_bounds__(256) void edge_enc_mfma(
    const float* __restrict__ attr, const float* __restrict__ noise,
    const int* __restrict__ perm,
    const float* __restrict__ w1, const float* __restrict__ b1,
    const u16* __restrict__ Wt2, const float* __restrict__ b2,
    u16* __restrict__ e)
{
  __shared__ __align__(16) u16 sT[64 * 128];
  __shared__ float sIn[64][8];
  __shared__ int sPerm[64];

  const int t = threadIdx.x;
  if (t < 64) sPerm[t] = perm[blockIdx.x * 64 + t];
  __syncthreads();

  for (int it = 0; it < 2; ++it) {
    int c = t + it * 256;
    int row = c >> 3, k = c & 7;
    int p = sPerm[row];
    sIn[row][k] = attr[(size_t)p * 8 + k] + noise[(size_t)p * 8 + k];
  }
  __syncthreads();

  // stage1: t1 = relu(in8 @ w1 + b1) -> swizzled bf16 tile
  {
    int f = t & 127;
    int r0 = (t >> 7) * 32;
    float wc[8];
    for (int k = 0; k < 8; ++k) wc[k] = w1[k * 128 + f];
    float bb = b1[f];
    for (int j = 0; j < 32; ++j) {
      int row = r0 + j;
      float a = bb;
      for (int k = 0; k < 8; ++k) a += sIn[row][k] * wc[k];
      sT[lad(row, f)] = f2bf(fmaxf(a, 0.f));
    }
  }
  __syncthreads();

  // stage2: e = t1 @ W2 + b2 (no relu), MFMA -> swizzled global tile
  const int lane = t & 63;
  const int wave = t >> 6;
  const int l16 = lane & 15;
  const int quad = lane >> 4;
  const int fb = wave * 32;
  f32x4 acc[2][4];
  for (int tt = 0; tt < 2; ++tt)
    for (int et = 0; et < 4; ++et) acc[tt][et] = zero4();
  gemm128(sT, Wt2, l16, quad, fb, acc);
  u16* etile = e + (size_t)blockIdx.x * 8192;
  for (int tt = 0; tt < 2; ++tt) {
    int f0 = fb + tt * 16 + quad * 4;
    float4 bb = *(const float4*)(b2 + f0);
    float bbv[4] = {bb.x, bb.y, bb.z, bb.w};
    for (int et = 0; et < 4; ++et) {
      int row = et * 16 + l16;
      float o[4];
      for (int r = 0; r < 4; ++r) o[r] = acc[tt][et][r] + bbv[r];
      *(uint2*)(etile + lad(row, f0)) = pack4bf(o);
    }
  }
}

// ---------------- per-layer node precompute -------------------------------
// reads h f32, converts to bf16 in-register; outputs:
// aib[n][0:128]=ai (f32), aib[n][128:256]=bi (f32), aj16[n][0:128]=aj (bf16)
// (aj bf16 gather validated rounds 1-8, same absmax class). 64 nodes/block.
__global__ __launch_bounds__(256) void nprep_kernel(
    const float* __restrict__ h, const u16* __restrict__ Wt_np,
    float* __restrict__ aib, u16* __restrict__ aj16)
{
  __shared__ __align__(16) u16 sH[64 * 128];
  const int t = threadIdx.x;
  const int n0 = blockIdx.x * 64;
  const int row = t >> 2;
  const int c0 = (t & 3) * 32;
  int n = n0 + row;
  const int nc = (n < NN) ? n : (NN - 1);

  const float* hp = h + (size_t)nc * 128 + c0;
  for (int k = 0; k < 32; k += 8) {
    float v[8];
    for (int r = 0; r < 8; ++r) v[r] = hp[k + r];
    uint4 uu;
    uu.x = cvt2(v[0], v[1]);
    uu.y = cvt2(v[2], v[3]);
    uu.z = cvt2(v[4], v[5]);
    uu.w = cvt2(v[6], v[7]);
    *(uint4*)(sH + lad(row, c0 + k)) = uu;
  }
  __syncthreads();

  const int lane = t & 63;
  const int wave = t >> 6;
  const int l16 = lane & 15;
  const int quad = lane >> 4;
  const int fb = wave * 96;  // 384 outputs / 4 waves
  f32x4 acc[6][4];
  for (int ft = 0; ft < 6; ++ft)
    for (int et = 0; et < 4; ++et) acc[ft][et] = zero4();
  for (int ks = 0; ks < 4; ++ks) {
    int kg = ks * 32 + quad * 8;
    bf16x8 b0 = ldbf(sH + lad(0 * 16 + l16, kg));
    bf16x8 b1 = ldbf(sH + lad(1 * 16 + l16, kg));
    bf16x8 b2 = ldbf(sH + lad(2 * 16 + l16, kg));
    bf16x8 b3 = ldbf(sH + lad(3 * 16 + l16, kg));
    for (int ft = 0; ft < 6; ++ft) {
      bf16x8 a = ldbf(Wt_np + (size_t)(fb + ft * 16 + l16) * 128 + kg);
      acc[ft][0] = __builtin_amdgcn_mfma_f32_16x16x32_bf16(a, b0, acc[ft][0], 0, 0, 0);
      acc[ft][1] = __builtin_amdgcn_mfma_f32_16x16x32_bf16(a, b1, acc[ft][1], 0, 0, 0);
      acc[ft][2] = __builtin_amdgcn_mfma_f32_16x16x32_bf16(a, b2, acc[ft][2], 0, 0, 0);
      acc[ft][3] = __builtin_amdgcn_mfma_f32_16x16x32_bf16(a, b3, acc[ft][3], 0, 0, 0);
    }
  }
  for (int ft = 0; ft < 6; ++ft) {
    int F = fb + ft * 16 + quad * 4;
    for (int et = 0; et < 4; ++et) {
      int n2 = n0 + et * 16 + l16;
      if (n2 >= NN) continue;
      if (F < 128) {
        *(f32x4*)(aib + (size_t)n2 * 256 + F) = acc[ft][et];
      } else if (F < 256) {
        float o[4] = {acc[ft][et][0], acc[ft][et][1], acc[ft][et][2], acc[ft][et][3]};
        *(uint2*)(aj16 + (size_t)n2 * 128 + (F - 128)) = pack4bf(o);
      } else {
        *(f32x4*)(aib + (size_t)n2 * 256 + (F - 128)) = acc[ft][et];
      }
    }
  }
}

// ---------------- fused GNN edge kernel: 128 sorted edges/block, 512 thr ----
// 8 waves x 16 features x 128 edges; 2 blocks/CU. aj gathered as bf16 from
// the L2-resident 5 MB aj16 array. write_e=0 on last layer skips e-LN+store.
__global__ __launch_bounds__(512, 4) void gnn_edge_mfma(
    u16* __restrict__ eg,                 // swizzled e tiles [NE/64][8192]
    const int* __restrict__ src_s, const int* __restrict__ dst_s,
    const float* __restrict__ aib,        // [NN][256] = [ai|bi] f32
    const u16* __restrict__ aj16,         // [NN][128] bf16
    const u16* __restrict__ Wt_e1c, const float* __restrict__ be1,
    const u16* __restrict__ Wt_e2,  const float* __restrict__ be2,
    const u16* __restrict__ Wt_n1b, const float* __restrict__ bn1,
    const u16* __restrict__ Wt_n2,
    const float* __restrict__ lng, const float* __restrict__ lnb,
    float* __restrict__ agg, int write_e)
{
  __shared__ __align__(16) char smem[74240];
  u16* sE = (u16*)smem;                    // [128][128] e -> e_new (32 KB)
  u16* sT = (u16*)(smem + 32768);          // [128][128] t1 -> t2   (32 KB)
  float* msgf = (float*)smem;              // 128x128 f32 overlay (64 KB)
  float* part_s = (float*)(smem + 65536);  // [8][128]
  float* part_q = (float*)(smem + 69632);  // [8][128]
  int* sDst = (int*)(smem + 73728);        // [128]

  const int t = threadIdx.x;
  const int e0 = blockIdx.x * 128;
  const int lane = t & 63;
  const int wave = t >> 6;   // 0..7
  const int l16 = lane & 15;
  const int quad = lane >> 4;
  const int fb = wave * 16;
  const int f0 = fb + quad * 4;

  if (t < 128) sDst[t] = dst_s[e0 + t];

  int rd[8], rs[8];
#pragma unroll
  for (int et = 0; et < 8; ++et) {
    rd[et] = dst_s[e0 + et * 16 + l16];
    rs[et] = src_s[e0 + et * 16 + l16];
  }

  // stage two consecutive 64-edge tiles = linear 32 KB; lad(row,col) with
  // row in 0..127 addresses them contiguously (row*128 + swz == tile layout)
  const u16* ebase = eg + (size_t)blockIdx.x * 16384;
#pragma unroll
  for (int it = 0; it < 4; ++it) {
    int c = it * 4096 + t * 8;
    *(us8*)(sE + c) = *(const us8*)(ebase + c);
  }
  __syncthreads();  // B1: sE + sDst ready

  // GEMM1: t1 = relu(e @ We1c + ai[dst] + aj[src] + be1), K=128
  f32x4 acc[8];
#pragma unroll
  for (int et = 0; et < 8; ++et) acc[et] = zero4();
  gemm128x8(sE, Wt_e1c, l16, quad, fb, acc);
  {
    float4 bb = *(const float4*)(be1 + f0);
    float bbv[4] = {bb.x, bb.y, bb.z, bb.w};
#pragma unroll
    for (int et = 0; et < 8; ++et) {
      f32x4 av = *(const f32x4*)(aib + (size_t)rd[et] * 256 + f0);
      uint2 jr = *(const uint2*)(aj16 + (size_t)rs[et] * 128 + f0);
      float jf[4];
      unpack4bf(jr, jf);
      int row = et * 16 + l16;
      float o[4];
      for (int r = 0; r < 4; ++r)
        o[r] = fmaxf(acc[et][r] + av[r] + jf[r] + bbv[r], 0.f);
      *(uint2*)(sT + lad(row, f0)) = pack4bf(o);
    }
  }
  __syncthreads();  // B2: sT(t1) ready

  // GEMM2: e_new = e + t1 @ We2 + be2 ; sE := e_new ; lnv folded into acc
#pragma unroll
  for (int et = 0; et < 8; ++et) acc[et] = zero4();
  gemm128x8(sT, Wt_e2, l16, quad, fb, acc);
  {
    float4 bb = *(const float4*)(be2 + f0);
    float bbv[4] = {bb.x, bb.y, bb.z, bb.w};
#pragma unroll
    for (int et = 0; et < 8; ++et) {
      int row = et * 16 + l16;
      float eo[4];
      unpack4bf(*(const uint2*)(sE + lad(row, f0)), eo);
      float en[4];
      for (int r = 0; r < 4; ++r) en[r] = eo[r] + acc[et][r] + bbv[r];
      *(uint2*)(sE + lad(row, f0)) = pack4bf(en);
      for (int r = 0; r < 4; ++r) acc[et][r] = eo[r] + en[r];  // lnv
    }
  }
  if (write_e) {
#pragma unroll
    for (int et = 0; et < 8; ++et) {
      float s = 0.f, q = 0.f;
      for (int r = 0; r < 4; ++r) {
        float v = acc[et][r];
        s += v; q += v * v;
      }
      s += __shfl_xor(s, 16); s += __shfl_xor(s, 32);
      q += __shfl_xor(q, 16); q += __shfl_xor(q, 32);
      if (quad == 0) {
        part_s[wave * 128 + et * 16 + l16] = s;
        part_q[wave * 128 + et * 16 + l16] = q;
      }
    }
  }
  __syncthreads();  // B3: parts + sE(e_new) ready; sT reads done

  // e-LN apply (lnv in acc) -> global e tile (bf16, swizzled)
  if (write_e) {
    u16* etile = eg + (size_t)blockIdx.x * 16384;
    float4 g4 = *(const float4*)(lng + f0);
    float4 b4 = *(const float4*)(lnb + f0);
    float gv[4] = {g4.x, g4.y, g4.z, g4.w};
    float bv[4] = {b4.x, b4.y, b4.z, b4.w};
#pragma unroll
    for (int et = 0; et < 8; ++et) {
      int row = et * 16 + l16;
      float s = 0.f, q = 0.f;
      for (int w = 0; w < 8; ++w) {
        s += part_s[w * 128 + row];
        q += part_q[w * 128 + row];
      }
      float m = s * (1.f / 128.f);
      float var = q * (1.f / 128.f) - m * m;
      float rsv = rsqrtf(fmaxf(var, 0.f) + 1e-5f);
      float o[4];
      for (int r = 0; r < 4; ++r)
        o[r] = (acc[et][r] - m) * rsv * gv[r] + bv[r];
      *(uint2*)(etile + lad(row, f0)) = pack4bf(o);
    }
  }

  // GEMM3: t2 = relu(e_new @ Wn1b + bi[dst] + bn1), K=128
#pragma unroll
  for (int et = 0; et < 8; ++et) acc[et] = zero4();
  gemm128x8(sE, Wt_n1b, l16, quad, fb, acc);
  {
    float4 bb = *(const float4*)(bn1 + f0);
    float bbv[4] = {bb.x, bb.y, bb.z, bb.w};
#pragma unroll
    for (int et = 0; et < 8; ++et) {
      f32x4 bv4 = *(const f32x4*)(aib + (size_t)rd[et] * 256 + 128 + f0);
      int row = et * 16 + l16;
      float o[4];
      for (int r = 0; r < 4; ++r)
        o[r] = fmaxf(acc[et][r] + bv4[r] + bbv[r], 0.f);
      *(uint2*)(sT + lad(row, f0)) = pack4bf(o);
    }
  }
  __syncthreads();  // B4: sT(t2) ready

  // GEMM4: msg_part = t2 @ Wn2 (xi and bn2 hoisted to node_ln)
#pragma unroll
  for (int et = 0; et < 8; ++et) acc[et] = zero4();
  gemm128x8(sT, Wt_n2, l16, quad, fb, acc);
  __syncthreads();  // B5: tiles dead -> msgf overlay (64 KB over sE+sT)

  {
    int c = f0 >> 2;  // wave*4 + quad, 0..31
#pragma unroll
    for (int et = 0; et < 8; ++et) {
      int row = et * 16 + l16;
      *(f32x4*)(msgf + row * 128 + (((c ^ (row & 31)) & 31) << 2)) = acc[et];
    }
  }
  __syncthreads();  // B6: msgf staged

  // segment reduction over sorted dst: 512 threads, 4 quarters of 32 rows
  {
    int f = t & 127, qtr = t >> 7;
    int c = f >> 2, c3 = f & 3;
    float a = 0.f;
    int j0 = qtr * 32;
    for (int j = j0; j < j0 + 32; ++j) {
      a += msgf[j * 128 + (((c ^ (j & 31)) & 31) << 2) + c3];
      int dj = sDst[j];
      if (j == j0 + 31 || sDst[j + 1] != dj) {
        atomicAdd(&agg[(size_t)dj * 128 + f], a);
        a = 0.f;
      }
    }
  }
}

// node layernorm: h = LN(h + agg + deg*(h + bn2)) -> h f32 ; agg = 0
__global__ void node_ln_kernel(float* h, float* agg,
                               const int* cnt, const float* bn2,
                               const float* g, const float* b) {
  __shared__ float red[128];
  int f = threadIdx.x;
  int n = blockIdx.x;
  long long base = (long long)n * 128 + f;
  float deg = (float)cnt[n];
  float hv = h[base];
  float v = hv + agg[base] + deg * (hv + bn2[f]);
  red[f] = v;
  __syncthreads();
  for (int s = 64; s > 0; s >>= 1) {
    if (f < s) red[f] += red[f + s];
    __syncthreads();
  }
  float m = red[0] * (1.0f / 128.0f);
  __syncthreads();
  red[f] = v * v;
  __syncthreads();
  for (int s = 64; s > 0; s >>= 1) {
    if (f < s) red[f] += red[f + s];
    __syncthreads();
  }
  float q = red[0] * (1.0f / 128.0f);
  float var = q - m * m;
  float rs = rsqrtf(fmaxf(var, 0.0f) + 1e-5f);
  float o = (v - m) * rs * g[f] + b[f];
  h[base] = o;
  agg[base] = 0.0f;
}

// decoder: out[n,:2] = mlp(h) - noise[:, :2] ; f32 out
__global__ void decoder_kernel(const float* h, const float* w1, const float* b1,
                               const float* w2, const float* b2,
                               const float* noise, float* out) {
  __shared__ float t1s[128];
  int f = threadIdx.x;
  int n = blockIdx.x;
  float a = b1[f];
  for (int k = 0; k < 128; ++k) a += h[(long long)n * 128 + k] * w1[k * 128 + f];
  t1s[f] = fmaxf(a, 0.0f);
  __syncthreads();
  if (f < 2) {
    float s = b2[f];
    for (int k = 0; k < 128; ++k) s += t1s[k] * w2[k * 2 + f];
    s -= noise[n * 16 + f];
    out[n * 2 + f] = s;
  }
}

extern "C" void kernel_launch(void* const* d_in, const int* in_sizes, int n_in,
                              void* d_out, int out_size, void* d_ws, size_t ws_size,
                              hipStream_t stream) {
  (void)in_sizes; (void)n_in; (void)out_size; (void)ws_size;

  const float* x      = (const float*)d_in[0];
  const float* eattr  = (const float*)d_in[1];
  const int*   eidx   = (const int*)d_in[2];
  const float* nnoise = (const float*)d_in[3];
  const float* enoise = (const float*)d_in[4];
  const float* ne_w1 = (const float*)d_in[5];  const float* ne_b1 = (const float*)d_in[6];
  const float* ne_w2 = (const float*)d_in[7];  const float* ne_b2 = (const float*)d_in[8];
  const float* ee_w1 = (const float*)d_in[9];  const float* ee_b1 = (const float*)d_in[10];
  const float* ee_w2 = (const float*)d_in[11]; const float* ee_b2 = (const float*)d_in[12];
  const float* ge_w1 = (const float*)d_in[13]; const float* ge_b1 = (const float*)d_in[14];
  const float* ge_w2 = (const float*)d_in[15]; const float* ge_b2 = (const float*)d_in[16];
  const float* gn_w1 = (const float*)d_in[17]; const float* gn_b1 = (const float*)d_in[18];
  const float* gn_w2 = (const float*)d_in[19]; const float* gn_b2 = (const float*)d_in[20];
  const float* xlng = (const float*)d_in[21]; const float* xlnb = (const float*)d_in[22];
  const float* elng = (const float*)d_in[23]; const float* elnb = (const float*)d_in[24];
  const float* d_w1 = (const float*)d_in[25]; const float* d_b1 = (const float*)d_in[26];
  const float* d_w2 = (const float*)d_in[27]; const float* d_b2 = (const float*)d_in[28];

  float* out = (float*)d_out;

  // workspace layout (~225 MB of 256 MB)
  char* base = (char*)d_ws;
  size_t off = 0;
  int* idx0 = (int*)(base + off);    off += (size_t)2 * NE * 4;
  int* src_s = (int*)(base + off);   off += (size_t)NE * 4;
  int* dst_s = (int*)(base + off);   off += (size_t)NE * 4;
  int* perm = (int*)(base + off);    off += (size_t)NE * 4;
  int* cnt = (int*)(base + off);     off += (size_t)NN * 4;
  int* cursor = (int*)(base + off);  off += (size_t)NN * 4;
  int* flag = (int*)(base + off);    off += 16;
  float* h = (float*)(base + off);   off += (size_t)NN * 128 * 4;
  float* agg = (float*)(base + off); off += (size_t)NN * 128 * 4;
  u16* e = (u16*)(base + off);       off += (size_t)NE * 128 * 2;  // swizzled tiles
  float* aib = (float*)(base + off); off += (size_t)NN * 256 * 4;
  u16* aj16 = (u16*)(base + off);    off += (size_t)NN * 128 * 2;
  u16* Wt_np = (u16*)(base + off);   off += (size_t)384 * 128 * 2;
  u16* Wt_e1c = (u16*)(base + off);  off += (size_t)128 * 128 * 2;
  u16* Wt_ge2 = (u16*)(base + off);  off += (size_t)128 * 128 * 2;
  u16* Wt_n1b = (u16*)(base + off);  off += (size_t)128 * 128 * 2;
  u16* Wt_gn2 = (u16*)(base + off);  off += (size_t)128 * 128 * 2;
  u16* Wt_ee2 = (u16*)(base + off);  off += (size_t)128 * 128 * 2;

  hipStreamCaptureStatus cs = hipStreamCaptureStatusNone;
  hipStreamIsCapturing(stream, &cs);
  const bool dbg = (cs == hipStreamCaptureStatusNone);

  const int* src0 = idx0;
  const int* dst0 = idx0 + NE;

  init_kernel<<<(NN * 128 + 255) / 256, 256, 0, stream>>>(agg, NN * 128, cnt, NN);
  idx_detect_kernel<<<1, 64, 0, stream>>>(eidx, flag);
  idx_prep_kernel<<<(2 * NE + 255) / 256, 256, 0, stream>>>(eidx, flag, idx0);

  // counting sort by dst (once; reused by all layers). cnt kept as degree.
  hist_kernel<<<(NE + 255) / 256, 256, 0, stream>>>(dst0, cnt);
  prefix_kernel<<<1, 1024, 0, stream>>>(cnt, cursor);
  scatter_kernel<<<(NE + 255) / 256, 256, 0, stream>>>(src0, dst0, cursor,
                                                       src_s, dst_s, perm);

  // weight slices (all [128 f][128 k] bf16, k contiguous)
  transpose_slice_kernel<<<64, 256, 0, stream>>>(ge_w1, Wt_np, 0);            // ai
  transpose_slice_kernel<<<64, 256, 0, stream>>>(ge_w1, Wt_np + 16384, 128);  // aj
  transpose_slice_kernel<<<64, 256, 0, stream>>>(gn_w1, Wt_np + 32768, 0);    // bi
  transpose_slice_kernel<<<64, 256, 0, stream>>>(ge_w1, Wt_e1c, 256);
  transpose_slice_kernel<<<64, 256, 0, stream>>>(ge_w2, Wt_ge2, 0);
  transpose_slice_kernel<<<64, 256, 0, stream>>>(gn_w1, Wt_n1b, 128);
  transpose_slice_kernel<<<64, 256, 0, stream>>>(gn_w2, Wt_gn2, 0);
  transpose_slice_kernel<<<64, 256, 0, stream>>>(ee_w2, Wt_ee2, 0);

  node_enc_kernel<<<NN, 128, 0, stream>>>(x, nnoise, ne_w1, ne_b1, ne_w2, ne_b2, h);
  edge_enc_mfma<<<NE / 64, 256, 0, stream>>>(eattr, enoise, perm,
                                             ee_w1, ee_b1, Wt_ee2, ee_b2, e);

  const int NB_N = (NN + 63) / 64;
  for (int l = 0; l < NL; ++l) {
    nprep_kernel<<<NB_N, 256, 0, stream>>>(h, Wt_np, aib, aj16);
    gnn_edge_mfma<<<NE / 128, 512, 0, stream>>>(e, src_s, dst_s, aib, aj16,
        Wt_e1c, ge_b1, Wt_ge2, ge_b2, Wt_n1b, gn_b1, Wt_gn2,
        elng + l * 128, elnb + l * 128, agg, (l < NL - 1) ? 1 : 0);
    node_ln_kernel<<<NN, 128, 0, stream>>>(h, agg, cnt, gn_b2,
                                           xlng + l * 128, xlnb + l * 128);
  }

  decoder_kernel<<<NN, 128, 0, stream>>>(h, d_w1, d_b1, d_w2, d_b2, nnoise, out);

  if (dbg) {
    hipStreamSynchronize(stream);
    float tbuf[6] = {0, 0, 0, 0, 0, 0};
    hipMemcpy(tbuf, h, 16, hipMemcpyDeviceToHost);
    hipMemcpy(tbuf + 4, out, 8, hipMemcpyDeviceToHost);
    fprintf(stderr, "KL r38 aj16: h[0..3]=%.5g %.5g %.5g %.5g out[0..1]=%.5g %.5g lasterr=%d\n",
            tbuf[0], tbuf[1], tbuf[2], tbuf[3], tbuf[4], tbuf[5], (int)hipGetLastError());
    fflush(stderr);
  }
}

// Round 18
// 2912.376 us; speedup vs baseline: 1.0053x; 1.0053x over previous
//
#include <hip/hip_runtime.h>
#include <stdio.h>

#define NN 20000
#define NE 640000
#define NL 10

typedef unsigned short u16;
typedef unsigned int u32;
typedef __attribute__((ext_vector_type(8))) __bf16 bf16x8;
typedef __attribute__((ext_vector_type(2))) __bf16 bf16x2;
typedef __attribute__((ext_vector_type(8))) unsigned short us8;
typedef __attribute__((ext_vector_type(4))) float f32x4;

__device__ __forceinline__ bf16x8 ldbf(const u16* p) {
  union { us8 u; bf16x8 b; } v;
  v.u = *(const us8*)p;
  return v.b;
}
__device__ __forceinline__ f32x4 zero4() {
  f32x4 z; z[0] = 0.f; z[1] = 0.f; z[2] = 0.f; z[3] = 0.f; return z;
}
__device__ __forceinline__ float bf2f(u16 u) {
  u32 x = ((u32)u) << 16;
  return __uint_as_float(x);
}
// native cast -> v_cvt_pk_bf16_f32 (RTNE, bit-identical to manual RNE)
__device__ __forceinline__ u16 f2bf(float f) {
  __bf16 b = (__bf16)f;
  union { __bf16 b; u16 u; } v;
  v.b = b;
  return v.u;
}
__device__ __forceinline__ u32 cvt2(float lo, float hi) {
  union { bf16x2 b; u32 u; } v;
  v.b[0] = (__bf16)lo; v.b[1] = (__bf16)hi;
  return v.u;
}
// swizzled LDS element index for a [R][128] bf16 tile; 16B-chunk XOR swizzle
// (valid for any row count; swizzle period is 16 rows)
__device__ __forceinline__ int lad(int row, int col) {
  return (row << 7) + ((((col >> 3) ^ (row & 15)) << 3) | (col & 7));
}
__device__ __forceinline__ uint2 pack4bf(const float f[4]) {
  uint2 u;
  u.x = cvt2(f[0], f[1]);
  u.y = cvt2(f[2], f[3]);
  return u;
}
__device__ __forceinline__ void unpack4bf(uint2 u, float f[4]) {
  f[0] = bf2f((u16)(u.x & 0xffffu)); f[1] = bf2f((u16)(u.x >> 16));
  f[2] = bf2f((u16)(u.y & 0xffffu)); f[3] = bf2f((u16)(u.y >> 16));
}

// stub-named kernel retained (inert).
__global__ void LearnedSimModel_28716151341396_kernel() {}

// zero agg + dst histogram counters
__global__ void init_kernel(float* agg, int agg_n, int* cnt, int cnt_n) {
  int i = blockIdx.x * 256 + threadIdx.x;
  if (i < agg_n) agg[i] = 0.0f;
  if (i < cnt_n) cnt[i] = 0;
}

__global__ void idx_detect_kernel(const int* raw, int* flag) {
  if (threadIdx.x == 0 && blockIdx.x == 0) {
    int any = 0;
    for (int k = 0; k < 16; ++k) any = any | raw[2 * k + 1];
    flag[0] = (any != 0) ? 1 : 0;  // 1 -> int32 storage
  }
}

__global__ void idx_prep_kernel(const int* raw, const int* flag, int* idx0) {
  int i = blockIdx.x * 256 + threadIdx.x;
  if (i < 2 * NE) {
    int v;
    if (flag[0] != 0) v = raw[i];
    else v = (int)(((const long long*)raw)[i]);
    if (v < 0) v = 0;
    if (v >= NN) v = NN - 1;
    idx0[i] = v;
  }
}

__global__ void hist_kernel(const int* dst0, int* cnt) {
  int i = blockIdx.x * 256 + threadIdx.x;
  if (i < NE) atomicAdd(&cnt[dst0[i]], 1);
}

// exclusive prefix sum of cnt[NN] -> cursor[NN] (single block, 1024 threads)
__global__ void prefix_kernel(const int* cnt, int* cursor) {
  __shared__ int buf[1024];
  __shared__ int carry;
  int t = threadIdx.x;
  if (t == 0) carry = 0;
  __syncthreads();
  for (int base = 0; base < NN; base += 1024) {
    int v = (base + t < NN) ? cnt[base + t] : 0;
    buf[t] = v;
    __syncthreads();
    for (int s = 1; s < 1024; s <<= 1) {
      int add = (t >= s) ? buf[t - s] : 0;
      __syncthreads();
      buf[t] += add;
      __syncthreads();
    }
    int excl = buf[t] - v + carry;
    if (base + t < NN) cursor[base + t] = excl;
    __syncthreads();
    if (t == 0) carry = carry + buf[1023];
    __syncthreads();
  }
}

// scatter edges into dst-sorted order; perm[pos] = original edge id
__global__ void scatter_kernel(const int* src0, const int* dst0, int* cursor,
                               int* src_s, int* dst_s, int* perm) {
  int i = blockIdx.x * 256 + threadIdx.x;
  if (i < NE) {
    int d = dst0[i];
    int pos = atomicAdd(&cursor[d], 1);
    perm[pos] = i;
    src_s[pos] = src0[i];
    dst_s[pos] = d;
  }
}

// 128x128 K-slice transpose: Wt[f*128+k] = f2bf(W[(koff+k)*128 + f])
__global__ void transpose_slice_kernel(const float* __restrict__ W,
                                       u16* __restrict__ Wt, int koff) {
  int i = blockIdx.x * 256 + threadIdx.x;  // i < 128*128
  int k = i >> 7, f = i & 127;
  Wt[f * 128 + k] = f2bf(W[(size_t)(koff + k) * 128 + f]);
}

// node encoder: h f32 only
__global__ void node_enc_kernel(const float* x, const float* noise,
                                const float* w1, const float* b1,
                                const float* w2, const float* b2,
                                float* h) {
  __shared__ float in16[16];
  __shared__ float t1s[128];
  int f = threadIdx.x;
  int n = blockIdx.x;
  if (f < 16) in16[f] = x[n * 16 + f] + noise[n * 16 + f];
  __syncthreads();
  float a = b1[f];
  for (int k = 0; k < 16; ++k) a += in16[k] * w1[k * 128 + f];
  t1s[f] = fmaxf(a, 0.0f);
  __syncthreads();
  float o = b2[f];
  for (int k = 0; k < 128; ++k) o += t1s[k] * w2[k * 128 + f];
  h[(long long)n * 128 + f] = o;
}

// per-wave GEMM over a [64][128] swizzled LDS tile; A = Wt (stride K=128)
__device__ __forceinline__ void gemm128(const u16* lds, const u16* Wt,
                                        int l16, int quad, int fb, f32x4 acc[2][4]) {
  for (int ks = 0; ks < 4; ++ks) {
    int kg = ks * 32 + quad * 8;
    bf16x8 b0 = ldbf(lds + lad(0 * 16 + l16, kg));
    bf16x8 b1 = ldbf(lds + lad(1 * 16 + l16, kg));
    bf16x8 b2 = ldbf(lds + lad(2 * 16 + l16, kg));
    bf16x8 b3 = ldbf(lds + lad(3 * 16 + l16, kg));
    for (int tt = 0; tt < 2; ++tt) {
      bf16x8 a = ldbf(Wt + (size_t)(fb + tt * 16 + l16) * 128 + kg);
      acc[tt][0] = __builtin_amdgcn_mfma_f32_16x16x32_bf16(a, b0, acc[tt][0], 0, 0, 0);
      acc[tt][1] = __builtin_amdgcn_mfma_f32_16x16x32_bf16(a, b1, acc[tt][1], 0, 0, 0);
      acc[tt][2] = __builtin_amdgcn_mfma_f32_16x16x32_bf16(a, b2, acc[tt][2], 0, 0, 0);
      acc[tt][3] = __builtin_amdgcn_mfma_f32_16x16x32_bf16(a, b3, acc[tt][3], 0, 0, 0);
    }
  }
}

// 8-wave/128-edge GEMM: wave owns 16 output features, 8 row-groups of 16 edges
__device__ __forceinline__ void gemm128x8(const u16* lds, const u16* Wt,
                                          int l16, int quad, int fb, f32x4 acc[8]) {
  for (int ks = 0; ks < 4; ++ks) {
    int kg = ks * 32 + quad * 8;
    bf16x8 a = ldbf(Wt + (size_t)(fb + l16) * 128 + kg);
#pragma unroll
    for (int et = 0; et < 8; ++et) {
      bf16x8 b = ldbf(lds + lad(et * 16 + l16, kg));
      acc[et] = __builtin_amdgcn_mfma_f32_16x16x32_bf16(a, b, acc[et], 0, 0, 0);
    }
  }
}

// ---------------- MFMA edge encoder: 64 sorted edges/block, 256 threads -----
// writes e in swizzled tile format: e_tile[b][lad(row,f)]
__global__ __launch_bounds__(256) void edge_enc_mfma(
    const float* __restrict__ attr, const float* __restrict__ noise,
    const int* __restrict__ perm,
    const float* __restrict__ w1, const float* __restrict__ b1,
    const u16* __restrict__ Wt2, const float* __restrict__ b2,
    u16* __restrict__ e)
{
  __shared__ __align__(16) u16 sT[64 * 128];
  __shared__ float sIn[64][8];
  __shared__ int sPerm[64];

  const int t = threadIdx.x;
  if (t < 64) sPerm[t] = perm[blockIdx.x * 64 + t];
  __syncthreads();

  for (int it = 0; it < 2; ++it) {
    int c = t + it * 256;
    int row = c >> 3, k = c & 7;
    int p = sPerm[row];
    sIn[row][k] = attr[(size_t)p * 8 + k] + noise[(size_t)p * 8 + k];
  }
  __syncthreads();

  // stage1: t1 = relu(in8 @ w1 + b1) -> swizzled bf16 tile
  {
    int f = t & 127;
    int r0 = (t >> 7) * 32;
    float wc[8];
    for (int k = 0; k < 8; ++k) wc[k] = w1[k * 128 + f];
    float bb = b1[f];
    for (int j = 0; j < 32; ++j) {
      int row = r0 + j;
      float a = bb;
      for (int k = 0; k < 8; ++k) a += sIn[row][k] * wc[k];
      sT[lad(row, f)] = f2bf(fmaxf(a, 0.f));
    }
  }
  __syncthreads();

  // stage2: e = t1 @ W2 + b2 (no relu), MFMA -> swizzled global tile
  const int lane = t & 63;
  const int wave = t >> 6;
  const int l16 = lane & 15;
  const int quad = lane >> 4;
  const int fb = wave * 32;
  f32x4 acc[2][4];
  for (int tt = 0; tt < 2; ++tt)
    for (int et = 0; et < 4; ++et) acc[tt][et] = zero4();
  gemm128(sT, Wt2, l16, quad, fb, acc);
  u16* etile = e + (size_t)blockIdx.x * 8192;
  for (int tt = 0; tt < 2; ++tt) {
    int f0 = fb + tt * 16 + quad * 4;
    float4 bb = *(const float4*)(b2 + f0);
    float bbv[4] = {bb.x, bb.y, bb.z, bb.w};
    for (int et = 0; et < 4; ++et) {
      int row = et * 16 + l16;
      float o[4];
      for (int r = 0; r < 4; ++r) o[r] = acc[tt][et][r] + bbv[r];
      *(uint2*)(etile + lad(row, f0)) = pack4bf(o);
    }
  }
}

// ---------------- per-layer node precompute: nprep = h @ [We1a|We1b|Wn1a] ---
// reads h f32, converts to bf16 in-register. nprep[n][0:128]=ai,
// [128:256]=aj, [256:384]=bi (f32). 64 nodes/block, 256 threads.
__global__ __launch_bounds__(256) void nprep_kernel(
    const float* __restrict__ h, const u16* __restrict__ Wt_np,
    float* __restrict__ nprep)
{
  __shared__ __align__(16) u16 sH[64 * 128];
  const int t = threadIdx.x;
  const int n0 = blockIdx.x * 64;
  const int row = t >> 2;
  const int c0 = (t & 3) * 32;
  int n = n0 + row;
  const int nc = (n < NN) ? n : (NN - 1);

  const float* hp = h + (size_t)nc * 128 + c0;
  for (int k = 0; k < 32; k += 8) {
    float v[8];
    for (int r = 0; r < 8; ++r) v[r] = hp[k + r];
    uint4 uu;
    uu.x = cvt2(v[0], v[1]);
    uu.y = cvt2(v[2], v[3]);
    uu.z = cvt2(v[4], v[5]);
    uu.w = cvt2(v[6], v[7]);
    *(uint4*)(sH + lad(row, c0 + k)) = uu;
  }
  __syncthreads();

  const int lane = t & 63;
  const int wave = t >> 6;
  const int l16 = lane & 15;
  const int quad = lane >> 4;
  const int fb = wave * 96;  // 384 outputs / 4 waves
  f32x4 acc[6][4];
  for (int ft = 0; ft < 6; ++ft)
    for (int et = 0; et < 4; ++et) acc[ft][et] = zero4();
  for (int ks = 0; ks < 4; ++ks) {
    int kg = ks * 32 + quad * 8;
    bf16x8 b0 = ldbf(sH + lad(0 * 16 + l16, kg));
    bf16x8 b1 = ldbf(sH + lad(1 * 16 + l16, kg));
    bf16x8 b2 = ldbf(sH + lad(2 * 16 + l16, kg));
    bf16x8 b3 = ldbf(sH + lad(3 * 16 + l16, kg));
    for (int ft = 0; ft < 6; ++ft) {
      bf16x8 a = ldbf(Wt_np + (size_t)(fb + ft * 16 + l16) * 128 + kg);
      acc[ft][0] = __builtin_amdgcn_mfma_f32_16x16x32_bf16(a, b0, acc[ft][0], 0, 0, 0);
      acc[ft][1] = __builtin_amdgcn_mfma_f32_16x16x32_bf16(a, b1, acc[ft][1], 0, 0, 0);
      acc[ft][2] = __builtin_amdgcn_mfma_f32_16x16x32_bf16(a, b2, acc[ft][2], 0, 0, 0);
      acc[ft][3] = __builtin_amdgcn_mfma_f32_16x16x32_bf16(a, b3, acc[ft][3], 0, 0, 0);
    }
  }
  for (int ft = 0; ft < 6; ++ft) {
    int F = fb + ft * 16 + quad * 4;
    for (int et = 0; et < 4; ++et) {
      int n2 = n0 + et * 16 + l16;
      if (n2 < NN) *(f32x4*)(nprep + (size_t)n2 * 384 + F) = acc[ft][et];
    }
  }
}

// ---------------- fused GNN edge kernel: 128 sorted edges/block, 512 thr ----
// 8 waves x 16 features x 128 edges; amortizes fixed per-phase latency over
// 2x edges; 2 blocks/CU. write_e=0 on the final layer skips dead e-LN+store.
__global__ __launch_bounds__(512, 4) void gnn_edge_mfma(
    u16* __restrict__ eg,                 // swizzled e tiles [NE/64][8192]
    const int* __restrict__ src_s, const int* __restrict__ dst_s,
    const float* __restrict__ nprep,      // [NN][384] = [ai|aj|bi] f32
    const u16* __restrict__ Wt_e1c, const float* __restrict__ be1,
    const u16* __restrict__ Wt_e2,  const float* __restrict__ be2,
    const u16* __restrict__ Wt_n1b, const float* __restrict__ bn1,
    const u16* __restrict__ Wt_n2,
    const float* __restrict__ lng, const float* __restrict__ lnb,
    float* __restrict__ agg, int write_e)
{
  __shared__ __align__(16) char smem[74240];
  u16* sE = (u16*)smem;                    // [128][128] e -> e_new (32 KB)
  u16* sT = (u16*)(smem + 32768);          // [128][128] t1 -> t2   (32 KB)
  float* msgf = (float*)smem;              // 128x128 f32 overlay (64 KB)
  float* part_s = (float*)(smem + 65536);  // [8][128]
  float* part_q = (float*)(smem + 69632);  // [8][128]
  int* sDst = (int*)(smem + 73728);        // [128]

  const int t = threadIdx.x;
  const int e0 = blockIdx.x * 128;
  const int lane = t & 63;
  const int wave = t >> 6;   // 0..7
  const int l16 = lane & 15;
  const int quad = lane >> 4;
  const int fb = wave * 16;
  const int f0 = fb + quad * 4;

  if (t < 128) sDst[t] = dst_s[e0 + t];

  int rd[8], rs[8];
#pragma unroll
  for (int et = 0; et < 8; ++et) {
    rd[et] = dst_s[e0 + et * 16 + l16];
    rs[et] = src_s[e0 + et * 16 + l16];
  }

  // stage two consecutive 64-edge tiles = linear 32 KB; lad(row,col) with
  // row in 0..127 addresses them contiguously (row*128 + swz == tile layout)
  const u16* ebase = eg + (size_t)blockIdx.x * 16384;
#pragma unroll
  for (int it = 0; it < 4; ++it) {
    int c = it * 4096 + t * 8;
    *(us8*)(sE + c) = *(const us8*)(ebase + c);
  }
  __syncthreads();  // B1: sE + sDst ready

  // GEMM1: t1 = relu(e @ We1c + ai[dst] + aj[src] + be1), K=128
  f32x4 acc[8];
#pragma unroll
  for (int et = 0; et < 8; ++et) acc[et] = zero4();
  gemm128x8(sE, Wt_e1c, l16, quad, fb, acc);
  {
    float4 bb = *(const float4*)(be1 + f0);
    float bbv[4] = {bb.x, bb.y, bb.z, bb.w};
#pragma unroll
    for (int et = 0; et < 8; ++et) {
      f32x4 av = *(const f32x4*)(nprep + (size_t)rd[et] * 384 + f0);
      f32x4 jv = *(const f32x4*)(nprep + (size_t)rs[et] * 384 + 128 + f0);
      int row = et * 16 + l16;
      float o[4];
      for (int r = 0; r < 4; ++r)
        o[r] = fmaxf(acc[et][r] + av[r] + jv[r] + bbv[r], 0.f);
      *(uint2*)(sT + lad(row, f0)) = pack4bf(o);
    }
  }
  __syncthreads();  // B2: sT(t1) ready

  // GEMM2: e_new = e + t1 @ We2 + be2 ; sE := e_new ; lnv folded into acc
#pragma unroll
  for (int et = 0; et < 8; ++et) acc[et] = zero4();
  gemm128x8(sT, Wt_e2, l16, quad, fb, acc);
  {
    float4 bb = *(const float4*)(be2 + f0);
    float bbv[4] = {bb.x, bb.y, bb.z, bb.w};
#pragma unroll
    for (int et = 0; et < 8; ++et) {
      int row = et * 16 + l16;
      float eo[4];
      unpack4bf(*(const uint2*)(sE + lad(row, f0)), eo);
      float en[4];
      for (int r = 0; r < 4; ++r) en[r] = eo[r] + acc[et][r] + bbv[r];
      *(uint2*)(sE + lad(row, f0)) = pack4bf(en);
      for (int r = 0; r < 4; ++r) acc[et][r] = eo[r] + en[r];  // lnv
    }
  }
  if (write_e) {
#pragma unroll
    for (int et = 0; et < 8; ++et) {
      float s = 0.f, q = 0.f;
      for (int r = 0; r < 4; ++r) {
        float v = acc[et][r];
        s += v; q += v * v;
      }
      s += __shfl_xor(s, 16); s += __shfl_xor(s, 32);
      q += __shfl_xor(q, 16); q += __shfl_xor(q, 32);
      if (quad == 0) {
        part_s[wave * 128 + et * 16 + l16] = s;
        part_q[wave * 128 + et * 16 + l16] = q;
      }
    }
  }
  __syncthreads();  // B3: parts + sE(e_new) ready; sT reads done

  // e-LN apply (lnv in acc) -> global e tile (bf16, swizzled)
  if (write_e) {
    u16* etile = eg + (size_t)blockIdx.x * 16384;
    float4 g4 = *(const float4*)(lng + f0);
    float4 b4 = *(const float4*)(lnb + f0);
    float gv[4] = {g4.x, g4.y, g4.z, g4.w};
    float bv[4] = {b4.x, b4.y, b4.z, b4.w};
#pragma unroll
    for (int et = 0; et < 8; ++et) {
      int row = et * 16 + l16;
      float s = 0.f, q = 0.f;
      for (int w = 0; w < 8; ++w) {
        s += part_s[w * 128 + row];
        q += part_q[w * 128 + row];
      }
      float m = s * (1.f / 128.f);
      float var = q * (1.f / 128.f) - m * m;
      float rsv = rsqrtf(fmaxf(var, 0.f) + 1e-5f);
      float o[4];
      for (int r = 0; r < 4; ++r)
        o[r] = (acc[et][r] - m) * rsv * gv[r] + bv[r];
      *(uint2*)(etile + lad(row, f0)) = pack4bf(o);
    }
  }

  // GEMM3: t2 = relu(e_new @ Wn1b + bi[dst] + bn1), K=128
#pragma unroll
  for (int et = 0; et < 8; ++et) acc[et] = zero4();
  gemm128x8(sE, Wt_n1b, l16, quad, fb, acc);
  {
    float4 bb = *(const float4*)(bn1 + f0);
    float bbv[4] = {bb.x, bb.y, bb.z, bb.w};
#pragma unroll
    for (int et = 0; et < 8; ++et) {
      f32x4 bv4 = *(const f32x4*)(nprep + (size_t)rd[et] * 384 + 256 + f0);
      int row = et * 16 + l16;
      float o[4];
      for (int r = 0; r < 4; ++r)
        o[r] = fmaxf(acc[et][r] + bv4[r] + bbv[r], 0.f);
      *(uint2*)(sT + lad(row, f0)) = pack4bf(o);
    }
  }
  __syncthreads();  // B4: sT(t2) ready

  // GEMM4: msg_part = t2 @ Wn2 (xi and bn2 hoisted to node_ln)
#pragma unroll
  for (int et = 0; et < 8; ++et) acc[et] = zero4();
  gemm128x8(sT, Wt_n2, l16, quad, fb, acc);
  __syncthreads();  // B5: tiles dead -> msgf overlay (64 KB over sE+sT)

  {
    int c = f0 >> 2;  // wave*4 + quad, 0..31
#pragma unroll
    for (int et = 0; et < 8; ++et) {
      int row = et * 16 + l16;
      *(f32x4*)(msgf + row * 128 + (((c ^ (row & 31)) & 31) << 2)) = acc[et];
    }
  }
  __syncthreads();  // B6: msgf staged

  // segment reduction over sorted dst: 512 threads, 4 quarters of 32 rows
  {
    int f = t & 127, qtr = t >> 7;
    int c = f >> 2, c3 = f & 3;
    float a = 0.f;
    int j0 = qtr * 32;
    for (int j = j0; j < j0 + 32; ++j) {
      a += msgf[j * 128 + (((c ^ (j & 31)) & 31) << 2) + c3];
      int dj = sDst[j];
      if (j == j0 + 31 || sDst[j + 1] != dj) {
        atomicAdd(&agg[(size_t)dj * 128 + f], a);
        a = 0.f;
      }
    }
  }
}

// node layernorm: h = LN(h + agg + deg*(h + bn2)) -> h f32 ; agg = 0
__global__ void node_ln_kernel(float* h, float* agg,
                               const int* cnt, const float* bn2,
                               const float* g, const float* b) {
  __shared__ float red[128];
  int f = threadIdx.x;
  int n = blockIdx.x;
  long long base = (long long)n * 128 + f;
  float deg = (float)cnt[n];
  float hv = h[base];
  float v = hv + agg[base] + deg * (hv + bn2[f]);
  red[f] = v;
  __syncthreads();
  for (int s = 64; s > 0; s >>= 1) {
    if (f < s) red[f] += red[f + s];
    __syncthreads();
  }
  float m = red[0] * (1.0f / 128.0f);
  __syncthreads();
  red[f] = v * v;
  __syncthreads();
  for (int s = 64; s > 0; s >>= 1) {
    if (f < s) red[f] += red[f + s];
    __syncthreads();
  }
  float q = red[0] * (1.0f / 128.0f);
  float var = q - m * m;
  float rs = rsqrtf(fmaxf(var, 0.0f) + 1e-5f);
  float o = (v - m) * rs * g[f] + b[f];
  h[base] = o;
  agg[base] = 0.0f;
}

// decoder: out[n,:2] = mlp(h) - noise[:, :2] ; f32 out
__global__ void decoder_kernel(const float* h, const float* w1, const float* b1,
                               const float* w2, const float* b2,
                               const float* noise, float* out) {
  __shared__ float t1s[128];
  int f = threadIdx.x;
  int n = blockIdx.x;
  float a = b1[f];
  for (int k = 0; k < 128; ++k) a += h[(long long)n * 128 + k] * w1[k * 128 + f];
  t1s[f] = fmaxf(a, 0.0f);
  __syncthreads();
  if (f < 2) {
    float s = b2[f];
    for (int k = 0; k < 128; ++k) s += t1s[k] * w2[k * 2 + f];
    s -= noise[n * 16 + f];
    out[n * 2 + f] = s;
  }
}

extern "C" void kernel_launch(void* const* d_in, const int* in_sizes, int n_in,
                              void* d_out, int out_size, void* d_ws, size_t ws_size,
                              hipStream_t stream) {
  (void)in_sizes; (void)n_in; (void)out_size; (void)ws_size;

  const float* x      = (const float*)d_in[0];
  const float* eattr  = (const float*)d_in[1];
  const int*   eidx   = (const int*)d_in[2];
  const float* nnoise = (const float*)d_in[3];
  const float* enoise = (const float*)d_in[4];
  const float* ne_w1 = (const float*)d_in[5];  const float* ne_b1 = (const float*)d_in[6];
  const float* ne_w2 = (const float*)d_in[7];  const float* ne_b2 = (const float*)d_in[8];
  const float* ee_w1 = (const float*)d_in[9];  const float* ee_b1 = (const float*)d_in[10];
  const float* ee_w2 = (const float*)d_in[11]; const float* ee_b2 = (const float*)d_in[12];
  const float* ge_w1 = (const float*)d_in[13]; const float* ge_b1 = (const float*)d_in[14];
  const float* ge_w2 = (const float*)d_in[15]; const float* ge_b2 = (const float*)d_in[16];
  const float* gn_w1 = (const float*)d_in[17]; const float* gn_b1 = (const float*)d_in[18];
  const float* gn_w2 = (const float*)d_in[19]; const float* gn_b2 = (const float*)d_in[20];
  const float* xlng = (const float*)d_in[21]; const float* xlnb = (const float*)d_in[22];
  const float* elng = (const float*)d_in[23]; const float* elnb = (const float*)d_in[24];
  const float* d_w1 = (const float*)d_in[25]; const float* d_b1 = (const float*)d_in[26];
  const float* d_w2 = (const float*)d_in[27]; const float* d_b2 = (const float*)d_in[28];

  float* out = (float*)d_out;

  // workspace layout (~229 MB of 256 MB)
  char* base = (char*)d_ws;
  size_t off = 0;
  int* idx0 = (int*)(base + off);    off += (size_t)2 * NE * 4;
  int* src_s = (int*)(base + off);   off += (size_t)NE * 4;
  int* dst_s = (int*)(base + off);   off += (size_t)NE * 4;
  int* perm = (int*)(base + off);    off += (size_t)NE * 4;
  int* cnt = (int*)(base + off);     off += (size_t)NN * 4;
  int* cursor = (int*)(base + off);  off += (size_t)NN * 4;
  int* flag = (int*)(base + off);    off += 16;
  float* h = (float*)(base + off);   off += (size_t)NN * 128 * 4;
  float* agg = (float*)(base + off); off += (size_t)NN * 128 * 4;
  u16* e = (u16*)(base + off);       off += (size_t)NE * 128 * 2;  // swizzled tiles
  float* nprep = (float*)(base + off); off += (size_t)NN * 384 * 4;
  u16* Wt_np = (u16*)(base + off);   off += (size_t)384 * 128 * 2;
  u16* Wt_e1c = (u16*)(base + off);  off += (size_t)128 * 128 * 2;
  u16* Wt_ge2 = (u16*)(base + off);  off += (size_t)128 * 128 * 2;
  u16* Wt_n1b = (u16*)(base + off);  off += (size_t)128 * 128 * 2;
  u16* Wt_gn2 = (u16*)(base + off);  off += (size_t)128 * 128 * 2;
  u16* Wt_ee2 = (u16*)(base + off);  off += (size_t)128 * 128 * 2;

  hipStreamCaptureStatus cs = hipStreamCaptureStatusNone;
  hipStreamIsCapturing(stream, &cs);
  const bool dbg = (cs == hipStreamCaptureStatusNone);

  const int* src0 = idx0;
  const int* dst0 = idx0 + NE;

  init_kernel<<<(NN * 128 + 255) / 256, 256, 0, stream>>>(agg, NN * 128, cnt, NN);
  idx_detect_kernel<<<1, 64, 0, stream>>>(eidx, flag);
  idx_prep_kernel<<<(2 * NE + 255) / 256, 256, 0, stream>>>(eidx, flag, idx0);

  // counting sort by dst (once; reused by all layers). cnt kept as degree.
  hist_kernel<<<(NE + 255) / 256, 256, 0, stream>>>(dst0, cnt);
  prefix_kernel<<<1, 1024, 0, stream>>>(cnt, cursor);
  scatter_kernel<<<(NE + 255) / 256, 256, 0, stream>>>(src0, dst0, cursor,
                                                       src_s, dst_s, perm);

  // weight slices (all [128 f][128 k] bf16, k contiguous)
  transpose_slice_kernel<<<64, 256, 0, stream>>>(ge_w1, Wt_np, 0);            // ai
  transpose_slice_kernel<<<64, 256, 0, stream>>>(ge_w1, Wt_np + 16384, 128);  // aj
  transpose_slice_kernel<<<64, 256, 0, stream>>>(gn_w1, Wt_np + 32768, 0);    // bi
  transpose_slice_kernel<<<64, 256, 0, stream>>>(ge_w1, Wt_e1c, 256);
  transpose_slice_kernel<<<64, 256, 0, stream>>>(ge_w2, Wt_ge2, 0);
  transpose_slice_kernel<<<64, 256, 0, stream>>>(gn_w1, Wt_n1b, 128);
  transpose_slice_kernel<<<64, 256, 0, stream>>>(gn_w2, Wt_gn2, 0);
  transpose_slice_kernel<<<64, 256, 0, stream>>>(ee_w2, Wt_ee2, 0);

  node_enc_kernel<<<NN, 128, 0, stream>>>(x, nnoise, ne_w1, ne_b1, ne_w2, ne_b2, h);
  edge_enc_mfma<<<NE / 64, 256, 0, stream>>>(eattr, enoise, perm,
                                             ee_w1, ee_b1, Wt_ee2, ee_b2, e);

  const int NB_N = (NN + 63) / 64;
  for (int l = 0; l < NL; ++l) {
    nprep_kernel<<<NB_N, 256, 0, stream>>>(h, Wt_np, nprep);
    gnn_edge_mfma<<<NE / 128, 512, 0, stream>>>(e, src_s, dst_s, nprep,
        Wt_e1c, ge_b1, Wt_ge2, ge_b2, Wt_n1b, gn_b1, Wt_gn2,
        elng + l * 128, elnb + l * 128, agg, (l < NL - 1) ? 1 : 0);
    node_ln_kernel<<<NN, 128, 0, stream>>>(h, agg, cnt, gn_b2,
                                           xlng + l * 128, xlnb + l * 128);
  }

  decoder_kernel<<<NN, 128, 0, stream>>>(h, d_w1, d_b1, d_w2, d_b2, nnoise, out);

  if (dbg) {
    hipStreamSynchronize(stream);
    float tbuf[6] = {0, 0, 0, 0, 0, 0};
    hipMemcpy(tbuf, h, 16, hipMemcpyDeviceToHost);
    hipMemcpy(tbuf + 4, out, 8, hipMemcpyDeviceToHost);
    fprintf(stderr, "KL r39 final-r14: h[0..3]=%.5g %.5g %.5g %.5g out[0..1]=%.5g %.5g lasterr=%d\n",
            tbuf[0], tbuf[1], tbuf[2], tbuf[3], tbuf[4], tbuf[5], (int)hipGetLastError());
    fflush(stderr);
  }
}